// Round 3
// baseline (251.024 us; speedup 1.0000x reference)
//
#include <hip/hip_runtime.h>
#include <math.h>

// Cost weights / focal params (match reference)
#define W_CLASS 1.0f
#define W_BBOX  5.0f
#define W_GIOU  2.0f
#define F_ALPHA 0.25f
#define F_EPS   1e-8f

#define RPW 4              // rows per wave; block = 4 waves -> 16 rows/block
typedef float vf4 __attribute__((ext_vector_type(4)));

// One fused kernel:
//  Phase A (per wave): softmax + focal class-cost table for its RPW rows,
//    written to wave-private LDS (no barrier needed — each wave consumes only
//    the rows it produced).
//  Phase B: cost matrix tile [16 rows x 256 targets], each thread covers 4
//    consecutive targets (float4 nontemporal store = 16 B/lane).
__global__ __launch_bounds__(256)
void fused_cost_kernel(const float* __restrict__ logits,       // [N,128]
                       const float4* __restrict__ pred_boxes,  // [N] cxcywh
                       const float4* __restrict__ tgt_bbox,    // [T] cxcywh
                       const int4*  __restrict__ tgt_ids4,     // [T/4]
                       float* __restrict__ out,                // [N,T]
                       int T, int N) {
    __shared__ float sdelta[16 * 128];   // 8 KB
    const int lane = threadIdx.x & 63;
    const int wave = threadIdx.x >> 6;
    const int nbase = blockIdx.y * 16 + wave * RPW;

    // ---- Phase A: class-cost rows into LDS (all lanes participate) ----
    #pragma unroll
    for (int r = 0; r < RPW; ++r) {
        const int n = nbase + r;
        if (n >= N) break;                         // uniform
        const float* row = logits + (size_t)n * 128;
        float x0 = row[lane];
        float x1 = row[lane + 64];

        float m = fmaxf(x0, x1);
        #pragma unroll
        for (int off = 32; off > 0; off >>= 1)
            m = fmaxf(m, __shfl_xor(m, off));

        float e0 = __expf(x0 - m);
        float e1 = __expf(x1 - m);
        float s = e0 + e1;
        #pragma unroll
        for (int off = 32; off > 0; off >>= 1)
            s += __shfl_xor(s, off);
        float inv = 1.0f / s;

        float p0 = e0 * inv, p1 = e1 * inv;
        float omp0 = 1.0f - p0;
        float d0 = F_ALPHA * omp0 * omp0 * (-__logf(p0 + F_EPS))
                 - (1.0f - F_ALPHA) * p0 * p0 * (-__logf(1.0f - p0 + F_EPS));
        float omp1 = 1.0f - p1;
        float d1 = F_ALPHA * omp1 * omp1 * (-__logf(p1 + F_EPS))
                 - (1.0f - F_ALPHA) * p1 * p1 * (-__logf(1.0f - p1 + F_EPS));

        // lane i -> bank i%32, 2 lanes/bank: conflict-free (2-way is free)
        sdelta[(wave * RPW + r) * 128 + lane]      = d0;
        sdelta[(wave * RPW + r) * 128 + lane + 64] = d1;
    }
    // No __syncthreads: each wave reads back only its own LDS rows.

    // ---- Phase B: cost tile ----
    const int t0 = blockIdx.x * 256 + lane * 4;
    const bool active = (t0 < T);          // T % 4 == 0: all-4-valid or none
    const int tt = active ? t0 : 0;

    float4 tb[4];
    tb[0] = tgt_bbox[tt + 0];
    tb[1] = tgt_bbox[tt + 1];
    tb[2] = tgt_bbox[tt + 2];
    tb[3] = tgt_bbox[tt + 3];
    const int4 ids = tgt_ids4[tt >> 2];
    const int id[4] = {ids.x, ids.y, ids.z, ids.w};

    float tx0[4], ty0[4], tx1[4], ty1[4], ta[4];
    #pragma unroll
    for (int j = 0; j < 4; ++j) {
        tx0[j] = tb[j].x - 0.5f * tb[j].z;
        ty0[j] = tb[j].y - 0.5f * tb[j].w;
        tx1[j] = tb[j].x + 0.5f * tb[j].z;
        ty1[j] = tb[j].y + 0.5f * tb[j].w;
        ta[j]  = (tx1[j] - tx0[j]) * (ty1[j] - ty0[j]);
    }

    #pragma unroll
    for (int r = 0; r < RPW; ++r) {
        const int n = nbase + r;
        if (n >= N) break;               // uniform
        const float4 pb = pred_boxes[n]; // wave-uniform -> scalar load
        const float px0 = pb.x - 0.5f * pb.z, py0 = pb.y - 0.5f * pb.w;
        const float px1 = pb.x + 0.5f * pb.z, py1 = pb.y + 0.5f * pb.w;
        const float pa  = (px1 - px0) * (py1 - py0);
        const float* __restrict__ drow = sdelta + (wave * RPW + r) * 128;

        float rr[4];
        #pragma unroll
        for (int j = 0; j < 4; ++j) {
            const float d = drow[id[j]];     // LDS gather, ~2 lanes/bank

            float cb = fabsf(pb.x - tb[j].x) + fabsf(pb.y - tb[j].y)
                     + fabsf(pb.z - tb[j].z) + fabsf(pb.w - tb[j].w);

            float ix0 = fmaxf(px0, tx0[j]), iy0 = fmaxf(py0, ty0[j]);
            float ix1 = fminf(px1, tx1[j]), iy1 = fminf(py1, ty1[j]);
            float iw = fmaxf(ix1 - ix0, 0.0f), ih = fmaxf(iy1 - iy0, 0.0f);
            float inter = iw * ih;
            float uni = pa + ta[j] - inter;

            float ex0 = fminf(px0, tx0[j]), ey0 = fminf(py0, ty0[j]);
            float ex1 = fmaxf(px1, tx1[j]), ey1 = fmaxf(py1, ty1[j]);
            float ea = (ex1 - ex0) * (ey1 - ey0);

            float giou = inter * __builtin_amdgcn_rcpf(uni)
                       - (ea - uni) * __builtin_amdgcn_rcpf(ea);

            rr[j] = W_BBOX * cb + W_CLASS * d - W_GIOU * giou;
        }

        if (active) {
            vf4 v = {rr[0], rr[1], rr[2], rr[3]};
            __builtin_nontemporal_store(
                v, (vf4*)(out + (size_t)n * T + t0));
        }
    }
}

extern "C" void kernel_launch(void* const* d_in, const int* in_sizes, int n_in,
                              void* d_out, int out_size, void* d_ws, size_t ws_size,
                              hipStream_t stream) {
    const float* pred_logits = (const float*)d_in[0];   // [16,900,128] f32
    const float* pred_boxes  = (const float*)d_in[1];   // [16,900,4]  f32
    const int*   tgt_ids     = (const int*)d_in[2];     // [3200] int32
    const float* tgt_bbox    = (const float*)d_in[3];   // [3200,4] f32
    float* out = (float*)d_out;

    const int N = in_sizes[1] / 4;   // bs*Q = 14400
    const int T = in_sizes[2];       // 3200

    dim3 grid((T + 255) / 256, (N + 15) / 16);
    fused_cost_kernel<<<grid, 256, 0, stream>>>(
        pred_logits, (const float4*)pred_boxes, (const float4*)tgt_bbox,
        (const int4*)tgt_ids, out, T, N);
}